// Round 11
// baseline (259.695 us; speedup 1.0000x reference)
//
#include <hip/hip_runtime.h>
#include <hip/hip_bf16.h>

typedef __attribute__((ext_vector_type(8))) short short8v;
typedef __attribute__((ext_vector_type(4))) float f32x4;

#define T_TOK 2048
#define HDIM  2048
#define IDIM  768
#define NGRP  8

__device__ __forceinline__ unsigned short f2b(float f){
  unsigned u = __float_as_uint(f);
  u = u + 0x7FFFu + ((u >> 16) & 1u);
  return (unsigned short)(u >> 16);
}
__device__ __forceinline__ float b2f(unsigned short s){
  return __uint_as_float(((unsigned)s) << 16);
}

// ---------------- Router ------------------------------------------------------
__global__ __launch_bounds__(256) void router_kernel(
    const float* __restrict__ x, const float* __restrict__ gw,
    const int* __restrict__ mg, float* __restrict__ wtg,
    unsigned short* __restrict__ xb)
{
  __shared__ float xs[4][2048];
  __shared__ float lg[4][32];
  int tid = threadIdx.x;
  int t0 = blockIdx.x * 4;

  #pragma unroll
  for (int k = 0; k < 8; k++){
    int idx = k*256 + tid;
    int tok = idx >> 9, wi = idx & 511;
    float4 v = ((const float4*)(x + (size_t)(t0 + tok)*HDIM))[wi];
    ((float4*)xs[tok])[wi] = v;
    ushort4 b; b.x=f2b(v.x); b.y=f2b(v.y); b.z=f2b(v.z); b.w=f2b(v.w);
    ((ushort4*)(xb + (size_t)(t0+tok)*HDIM))[wi] = b;
  }
  __syncthreads();

  int e = tid >> 3, ch = tid & 7;
  float s0=0.f, s1=0.f, s2=0.f, s3=0.f;
  const float4* gv = (const float4*)(gw + (size_t)e*HDIM);
  #pragma unroll 4
  for (int k = 0; k < 64; k++){
    int i4 = ch + 8*k;
    float4 b  = gv[i4];
    float4 a0 = ((const float4*)xs[0])[i4];
    float4 a1 = ((const float4*)xs[1])[i4];
    float4 a2 = ((const float4*)xs[2])[i4];
    float4 a3 = ((const float4*)xs[3])[i4];
    s0 += a0.x*b.x + a0.y*b.y + a0.z*b.z + a0.w*b.w;
    s1 += a1.x*b.x + a1.y*b.y + a1.z*b.z + a1.w*b.w;
    s2 += a2.x*b.x + a2.y*b.y + a2.z*b.z + a2.w*b.w;
    s3 += a3.x*b.x + a3.y*b.y + a3.z*b.z + a3.w*b.w;
  }
  #pragma unroll
  for (int off=1; off<8; off<<=1){
    s0 += __shfl_xor(s0, off); s1 += __shfl_xor(s1, off);
    s2 += __shfl_xor(s2, off); s3 += __shfl_xor(s3, off);
  }
  if (ch == 0){ lg[0][e]=s0; lg[1][e]=s1; lg[2][e]=s2; lg[3][e]=s3; }
  __syncthreads();

  int wv = tid >> 6, lane = tid & 63;
  float val = (lane < 32) ? lg[wv][lane] : -1e30f;
  float mx = val;
  #pragma unroll
  for (int off=16; off; off>>=1) mx = fmaxf(mx, __shfl_xor(mx, off));
  float p = (lane < 32) ? expf(val - mx) : 0.f;
  float sm = p;
  #pragma unroll
  for (int off=16; off; off>>=1) sm += __shfl_xor(sm, off);
  float v = (lane < 32) ? (p / sm) : -1.f;
  int idx = lane;
  float vals[8]; int idxs[8];
  #pragma unroll
  for (int it=0; it<8; it++){
    float bv = v; int bi = idx;
    #pragma unroll
    for (int off=32; off; off>>=1){
      float ov = __shfl_xor(bv, off); int oi = __shfl_xor(bi, off);
      if (ov > bv || (ov == bv && oi < bi)){ bv = ov; bi = oi; }
    }
    vals[it] = bv; idxs[it] = bi;
    if (lane == bi) v = -1.f;
  }
  float tot = vals[0]+vals[1]+vals[2]+vals[3]+vals[4]+vals[5]+vals[6]+vals[7];
  float racc = 0.f;
  #pragma unroll
  for (int it=0; it<8; it++){
    int grp = mg[idxs[it]];
    if (lane == grp) racc += vals[it] / tot;
  }
  if (lane < 8) wtg[(size_t)(t0+wv)*NGRP + lane] = racc;
}

// ------- Merged convert: gu' (gate/up interleave) + dn, one launch -------------
__global__ __launch_bounds__(256) void convert_kernel(
    const float* __restrict__ gup, const float* __restrict__ dnp,
    unsigned short* __restrict__ gub, unsigned short* __restrict__ dnb,
    const int* __restrict__ de)
{
  int g = blockIdx.z;
  int bx = blockIdx.x;
  if (bx < 3072){
    int i4 = bx*256 + threadIdx.x;
    int j  = i4 >> 9;
    int c4 = i4 & 511;
    int q = j >> 5, r = j & 31;
    int srow = (r < 16) ? (q*16 + r) : (768 + q*16 + (r - 16));
    const float4* s = (const float4*)(gup + ((size_t)de[g]*1536 + srow)*HDIM);
    float4 vv = s[c4];
    ushort4 b; b.x=f2b(vv.x); b.y=f2b(vv.y); b.z=f2b(vv.z); b.w=f2b(vv.w);
    ((ushort4*)(gub + ((size_t)g*1536 + j)*HDIM))[c4] = b;
  } else {
    size_t i4 = (size_t)(bx - 3072)*256 + threadIdx.x;
    const float4* s = (const float4*)(dnp + (size_t)de[g]*1572864);
    float4 vv = s[i4];
    ushort4 b; b.x=f2b(vv.x); b.y=f2b(vv.y); b.z=f2b(vv.z); b.w=f2b(vv.w);
    ((ushort4*)(dnb + (size_t)g*1572864))[i4] = b;
  }
}

// ============== GEMM machinery =================================================

// 256-thread stager: R x 32 bf16 tile (64B rows), linear LDS. R/64 vm-ops/thread.
template<int R>
__device__ __forceinline__ void stage256(const unsigned short* __restrict__ gsrc,
                                         int ldE, unsigned short* __restrict__ lds,
                                         int tid)
{
  #pragma unroll
  for (int j = 0; j < R/64; j++){
    int row = j*64 + (tid >> 2);
    const unsigned short* src = gsrc + (size_t)row*ldE + (tid & 3)*8;
    __builtin_amdgcn_global_load_lds(
        (const __attribute__((address_space(1))) void*)src,
        (__attribute__((address_space(3))) void*)(lds + j*2048 + (tid >> 6)*512),
        16, 0, 0);
  }
}

// 512-thread stager: R/128 vm-ops/thread.
template<int R>
__device__ __forceinline__ void stage512(const unsigned short* __restrict__ gsrc,
                                         int ldE, unsigned short* __restrict__ lds,
                                         int tid)
{
  #pragma unroll
  for (int j = 0; j < R/128; j++){
    int row = j*128 + (tid >> 2);
    const unsigned short* src = gsrc + (size_t)row*ldE + (tid & 3)*8;
    __builtin_amdgcn_global_load_lds(
        (const __attribute__((address_space(1))) void*)src,
        (__attribute__((address_space(3))) void*)(lds + j*4096 + (tid >> 6)*512),
        16, 0, 0);
  }
}

__device__ __forceinline__ short8v rfrag(const unsigned short* lds, int r, int s){
  return *(const short8v*)((const char*)lds + r*64 + (s << 4));
}

#define WAITV(N)  asm volatile("s_waitcnt vmcnt(" #N ")" ::: "memory")
#define TOPBAR()  do { __builtin_amdgcn_s_barrier(); __builtin_amdgcn_sched_barrier(0); } while(0)
#define PIN()     do { asm volatile("s_waitcnt lgkmcnt(0)" ::: "memory"); __builtin_amdgcn_sched_barrier(0); } while(0)

// ------ GEMM1 + fused SwiGLU (r5's proven kernel): 512 thr, 8 waves ------------
// BM=256, BN=128, wave 64x64 (4Mx2N), ring-4, dist-3, 3 vm-ops/tile,
// ladder WAITV(6)/6/3/0, grid 768 = 3 rounds.
__global__ __launch_bounds__(512, 2) void gemm1_kernel(
    const unsigned short* __restrict__ xb, const unsigned short* __restrict__ gu,
    const float* __restrict__ wtg, unsigned short* __restrict__ actb)
{
  __shared__ unsigned short Al[4][8192];   // 4 x 16 KB
  __shared__ unsigned short Bl[4][4096];   // 4 x  8 KB
  int tid = threadIdx.x, lane = tid & 63, w = tid >> 6;
  int wm = w >> 1, wn = w & 1;
  int fr = lane & 15, sl = lane >> 4;

  int bid = blockIdx.x;
  int xcd = bid & 7, j = bid >> 3;
  int panel = ((xcd & 1) ? 48 : 0) + (j >> 1);
  int mb = ((xcd >> 1) << 1) + (j & 1);
  int nb = panel % 12, g = panel / 12;
  int m0 = mb * 256, n0 = nb * 128;
  const unsigned short* Abase = xb + (size_t)m0 * HDIM;
  const unsigned short* Bbase = gu + ((size_t)g * 1536 + n0) * HDIM;

  f32x4 acc[4][4];
  #pragma unroll
  for (int m=0;m<4;m++){
    #pragma unroll
    for (int n=0;n<4;n++) acc[m][n] = (f32x4){0,0,0,0};
  }

  #define BODY1(t, DOSTAGE) do { \
    int buf = (t) & 3; \
    short8v av[4], bv[4]; \
    _Pragma("unroll") for (int m=0;m<4;m++) av[m] = rfrag(&Al[buf][0], wm*64 + m*16 + fr, sl); \
    _Pragma("unroll") for (int n=0;n<4;n++) bv[n] = rfrag(&Bl[buf][0], wn*64 + n*16 + fr, sl); \
    if (DOSTAGE){ int k2 = (t)+3, b2 = k2 & 3; \
      stage512<256>(Abase + k2*32, HDIM, &Al[b2][0], tid); \
      stage512<128>(Bbase + k2*32, HDIM, &Bl[b2][0], tid); } \
    PIN(); \
    __builtin_amdgcn_s_setprio(1); \
    _Pragma("unroll") for (int m=0;m<4;m++){ \
      _Pragma("unroll") for (int n=0;n<4;n++){ \
        acc[m][n] = __builtin_amdgcn_mfma_f32_16x16x32_bf16(av[m], bv[n], acc[m][n],0,0,0); } } \
    __builtin_amdgcn_s_setprio(0); \
  } while(0)

  const int NT = 64;
  stage512<256>(Abase,      HDIM, &Al[0][0], tid); stage512<128>(Bbase,      HDIM, &Bl[0][0], tid);
  stage512<256>(Abase + 32, HDIM, &Al[1][0], tid); stage512<128>(Bbase + 32, HDIM, &Bl[1][0], tid);
  stage512<256>(Abase + 64, HDIM, &Al[2][0], tid); stage512<128>(Bbase + 64, HDIM, &Bl[2][0], tid);

  for (int t = 0; t < NT-3; ++t){
    WAITV(6); TOPBAR();
    BODY1(t, 1);
  }
  WAITV(6); TOPBAR(); BODY1(NT-3, 0);
  WAITV(3); TOPBAR(); BODY1(NT-2, 0);
  WAITV(0); TOPBAR(); BODY1(NT-1, 0);
  #undef BODY1

  // fused SwiGLU epilogue: n-frags [gate,up,gate,up] by construction of gu'
  int r0 = (lane >> 4) * 4;
  int q0 = (n0 + wn*64) >> 5;
  #pragma unroll
  for (int m = 0; m < 4; m++){
    int trow = m0 + wm*64 + m*16 + r0;
    #pragma unroll
    for (int q = 0; q < 2; q++){
      int icol = (q0 + q)*16 + fr;
      #pragma unroll
      for (int jj = 0; jj < 4; jj++){
        int t = trow + jj;
        float wv = wtg[(size_t)t*NGRP + g];
        float gf = acc[m][2*q][jj];
        float uf = acc[m][2*q+1][jj];
        float sg = gf / (1.f + expf(-gf));
        actb[((size_t)g*T_TOK + t)*IDIM + icol] = f2b(sg * uf * wv);
      }
    }
  }
}

// ------ GEMM2 single-shot: out = ACT(2048 x 6144) x DN^T, K = 8 groups x 768 ----
// BM=BN=128, 256 thr, 4 waves (2Mx2N, wave 64x64), ring-4 (64KB), dist-3,
// 4 vm-ops/tile, ladder WAITV(8)/8/4/0, NT=192, grid 256 = 1 round.
// No split-K, no partials: writes f32 directly to d_out.
__global__ __launch_bounds__(256, 2) void gemm2_kernel(
    const unsigned short* __restrict__ actb, const unsigned short* __restrict__ dnb,
    float* __restrict__ out)
{
  __shared__ unsigned short Al[4][4096];   // 4 x 8 KB (128x32)
  __shared__ unsigned short Bl[4][4096];   // 4 x 8 KB (128x32)
  int tid = threadIdx.x, lane = tid & 63, w = tid >> 6;
  int wm = w >> 1, wn = w & 1;
  int fr = lane & 15, sl = lane >> 4;

  // XCD mapping: each XCD owns 2 mb-slices x all 16 nb -> A panels L2-resident
  int bid = blockIdx.x;
  int xcd = bid & 7, j = bid >> 3;            // j 0..31
  int mb = (xcd << 1) | (j >> 4);             // 0..15
  int nb = j & 15;                            // 0..15
  int m0 = mb * 128, n0 = nb * 128;

  f32x4 acc[4][4];
  #pragma unroll
  for (int m=0;m<4;m++){
    #pragma unroll
    for (int n=0;n<4;n++) acc[m][n] = (f32x4){0,0,0,0};
  }

  // tile kt (0..191): g = kt/24, i0 = (kt%24)*32  (768/32=24 -> no straddle)
  #define STAGE2(kt, b2) do { \
    int gi = (kt) / 24; int kk = ((kt) - gi*24) * 32; \
    stage256<128>(actb + ((size_t)(gi*T_TOK + m0))*IDIM + kk, IDIM, &Al[b2][0], tid); \
    stage256<128>(dnb  + ((size_t)(gi*HDIM + n0))*IDIM + kk, IDIM, &Bl[b2][0], tid); \
  } while(0)

  #define BODY2(t, DOSTAGE) do { \
    int buf = (t) & 3; \
    short8v av[4], bv[4]; \
    _Pragma("unroll") for (int m=0;m<4;m++) av[m] = rfrag(&Al[buf][0], wm*64 + m*16 + fr, sl); \
    _Pragma("unroll") for (int n=0;n<4;n++) bv[n] = rfrag(&Bl[buf][0], wn*64 + n*16 + fr, sl); \
    if (DOSTAGE){ int k2 = (t)+3; STAGE2(k2, k2 & 3); } \
    PIN(); \
    __builtin_amdgcn_s_setprio(1); \
    _Pragma("unroll") for (int m=0;m<4;m++){ \
      _Pragma("unroll") for (int n=0;n<4;n++){ \
        acc[m][n] = __builtin_amdgcn_mfma_f32_16x16x32_bf16(av[m], bv[n], acc[m][n],0,0,0); } } \
    __builtin_amdgcn_s_setprio(0); \
  } while(0)

  const int NT = 192;
  STAGE2(0, 0); STAGE2(1, 1); STAGE2(2, 2);

  for (int t = 0; t < NT-3; ++t){
    WAITV(8); TOPBAR();
    BODY2(t, 1);
  }
  WAITV(8); TOPBAR(); BODY2(NT-3, 0);
  WAITV(4); TOPBAR(); BODY2(NT-2, 0);
  WAITV(0); TOPBAR(); BODY2(NT-1, 0);
  #undef BODY2
  #undef STAGE2

  int r0 = (lane >> 4) * 4;
  #pragma unroll
  for (int m = 0; m < 4; m++){
    int row = m0 + wm*64 + m*16 + r0;
    #pragma unroll
    for (int n = 0; n < 4; n++){
      int cc = n0 + wn*64 + n*16 + fr;
      #pragma unroll
      for (int jj = 0; jj < 4; jj++){
        out[(size_t)(row + jj)*HDIM + cc] = acc[m][n][jj];
      }
    }
  }
}

extern "C" void kernel_launch(void* const* d_in, const int* in_sizes, int n_in,
                              void* d_out, int out_size, void* d_ws, size_t ws_size,
                              hipStream_t stream)
{
  (void)in_sizes; (void)n_in; (void)out_size; (void)ws_size;
  const float* x   = (const float*)d_in[0];
  const float* gw  = (const float*)d_in[1];
  const float* gup = (const float*)d_in[2];
  const float* dnp = (const float*)d_in[3];
  const int*   mg  = (const int*)d_in[4];
  const int*   de  = (const int*)d_in[5];
  float* out = (float*)d_out;
  char* ws = (char*)d_ws;

  // layout: [wtg 64K][xb 8M][dnb 24M][actb 24M][gub 48M]
  float*          wtg  = (float*)(ws + 0);
  unsigned short* xb   = (unsigned short*)(ws + 65536);
  unsigned short* dnb  = (unsigned short*)(ws + 8454144);
  unsigned short* actb = (unsigned short*)(ws + 33619968);
  unsigned short* gub  = (unsigned short*)(ws + 58785792);

  router_kernel<<<512, 256, 0, stream>>>(x, gw, mg, wtg, xb);
  convert_kernel<<<dim3(4608,1,8), 256, 0, stream>>>(gup, dnp, gub, dnb, de);
  gemm1_kernel<<<768, 512, 0, stream>>>(xb, gub, wtg, actb);
  gemm2_kernel<<<256, 256, 0, stream>>>(actb, dnb, out);
}

// Round 12
// 242.970 us; speedup vs baseline: 1.0688x; 1.0688x over previous
//
#include <hip/hip_runtime.h>
#include <hip/hip_bf16.h>

typedef __attribute__((ext_vector_type(8))) short short8v;
typedef __attribute__((ext_vector_type(4))) float f32x4;

#define T_TOK 2048
#define HDIM  2048
#define IDIM  768
#define NGRP  8

__device__ __forceinline__ unsigned short f2b(float f){
  unsigned u = __float_as_uint(f);
  u = u + 0x7FFFu + ((u >> 16) & 1u);
  return (unsigned short)(u >> 16);
}
__device__ __forceinline__ float b2f(unsigned short s){
  return __uint_as_float(((unsigned)s) << 16);
}

// ---------------- Router ------------------------------------------------------
__global__ __launch_bounds__(256) void router_kernel(
    const float* __restrict__ x, const float* __restrict__ gw,
    const int* __restrict__ mg, float* __restrict__ wtg,
    unsigned short* __restrict__ xb)
{
  __shared__ float xs[4][2048];
  __shared__ float lg[4][32];
  int tid = threadIdx.x;
  int t0 = blockIdx.x * 4;

  #pragma unroll
  for (int k = 0; k < 8; k++){
    int idx = k*256 + tid;
    int tok = idx >> 9, wi = idx & 511;
    float4 v = ((const float4*)(x + (size_t)(t0 + tok)*HDIM))[wi];
    ((float4*)xs[tok])[wi] = v;
    ushort4 b; b.x=f2b(v.x); b.y=f2b(v.y); b.z=f2b(v.z); b.w=f2b(v.w);
    ((ushort4*)(xb + (size_t)(t0+tok)*HDIM))[wi] = b;
  }
  __syncthreads();

  int e = tid >> 3, ch = tid & 7;
  float s0=0.f, s1=0.f, s2=0.f, s3=0.f;
  const float4* gv = (const float4*)(gw + (size_t)e*HDIM);
  #pragma unroll 4
  for (int k = 0; k < 64; k++){
    int i4 = ch + 8*k;
    float4 b  = gv[i4];
    float4 a0 = ((const float4*)xs[0])[i4];
    float4 a1 = ((const float4*)xs[1])[i4];
    float4 a2 = ((const float4*)xs[2])[i4];
    float4 a3 = ((const float4*)xs[3])[i4];
    s0 += a0.x*b.x + a0.y*b.y + a0.z*b.z + a0.w*b.w;
    s1 += a1.x*b.x + a1.y*b.y + a1.z*b.z + a1.w*b.w;
    s2 += a2.x*b.x + a2.y*b.y + a2.z*b.z + a2.w*b.w;
    s3 += a3.x*b.x + a3.y*b.y + a3.z*b.z + a3.w*b.w;
  }
  #pragma unroll
  for (int off=1; off<8; off<<=1){
    s0 += __shfl_xor(s0, off); s1 += __shfl_xor(s1, off);
    s2 += __shfl_xor(s2, off); s3 += __shfl_xor(s3, off);
  }
  if (ch == 0){ lg[0][e]=s0; lg[1][e]=s1; lg[2][e]=s2; lg[3][e]=s3; }
  __syncthreads();

  int wv = tid >> 6, lane = tid & 63;
  float val = (lane < 32) ? lg[wv][lane] : -1e30f;
  float mx = val;
  #pragma unroll
  for (int off=16; off; off>>=1) mx = fmaxf(mx, __shfl_xor(mx, off));
  float p = (lane < 32) ? expf(val - mx) : 0.f;
  float sm = p;
  #pragma unroll
  for (int off=16; off; off>>=1) sm += __shfl_xor(sm, off);
  float v = (lane < 32) ? (p / sm) : -1.f;
  int idx = lane;
  float vals[8]; int idxs[8];
  #pragma unroll
  for (int it=0; it<8; it++){
    float bv = v; int bi = idx;
    #pragma unroll
    for (int off=32; off; off>>=1){
      float ov = __shfl_xor(bv, off); int oi = __shfl_xor(bi, off);
      if (ov > bv || (ov == bv && oi < bi)){ bv = ov; bi = oi; }
    }
    vals[it] = bv; idxs[it] = bi;
    if (lane == bi) v = -1.f;
  }
  float tot = vals[0]+vals[1]+vals[2]+vals[3]+vals[4]+vals[5]+vals[6]+vals[7];
  float racc = 0.f;
  #pragma unroll
  for (int it=0; it<8; it++){
    int grp = mg[idxs[it]];
    if (lane == grp) racc += vals[it] / tot;
  }
  if (lane < 8) wtg[(size_t)(t0+wv)*NGRP + lane] = racc;
}

// ------- Merged convert: gu' (gate/up interleave) + dn, one launch -------------
__global__ __launch_bounds__(256) void convert_kernel(
    const float* __restrict__ gup, const float* __restrict__ dnp,
    unsigned short* __restrict__ gub, unsigned short* __restrict__ dnb,
    const int* __restrict__ de)
{
  int g = blockIdx.z;
  int bx = blockIdx.x;
  if (bx < 3072){
    int i4 = bx*256 + threadIdx.x;
    int j  = i4 >> 9;
    int c4 = i4 & 511;
    int q = j >> 5, r = j & 31;
    int srow = (r < 16) ? (q*16 + r) : (768 + q*16 + (r - 16));
    const float4* s = (const float4*)(gup + ((size_t)de[g]*1536 + srow)*HDIM);
    float4 vv = s[c4];
    ushort4 b; b.x=f2b(vv.x); b.y=f2b(vv.y); b.z=f2b(vv.z); b.w=f2b(vv.w);
    ((ushort4*)(gub + ((size_t)g*1536 + j)*HDIM))[c4] = b;
  } else {
    size_t i4 = (size_t)(bx - 3072)*256 + threadIdx.x;
    const float4* s = (const float4*)(dnp + (size_t)de[g]*1572864);
    float4 vv = s[i4];
    ushort4 b; b.x=f2b(vv.x); b.y=f2b(vv.y); b.z=f2b(vv.z); b.w=f2b(vv.w);
    ((ushort4*)(dnb + (size_t)g*1572864))[i4] = b;
  }
}

// ============== GEMM machinery =================================================

// 256-thread stager: R x 32 bf16 tile (64B rows), linear LDS. R/64 vm-ops/thread.
template<int R>
__device__ __forceinline__ void stage256(const unsigned short* __restrict__ gsrc,
                                         int ldE, unsigned short* __restrict__ lds,
                                         int tid)
{
  #pragma unroll
  for (int j = 0; j < R/64; j++){
    int row = j*64 + (tid >> 2);
    const unsigned short* src = gsrc + (size_t)row*ldE + (tid & 3)*8;
    __builtin_amdgcn_global_load_lds(
        (const __attribute__((address_space(1))) void*)src,
        (__attribute__((address_space(3))) void*)(lds + j*2048 + (tid >> 6)*512),
        16, 0, 0);
  }
}

// 512-thread stager: R/128 vm-ops/thread.
template<int R>
__device__ __forceinline__ void stage512(const unsigned short* __restrict__ gsrc,
                                         int ldE, unsigned short* __restrict__ lds,
                                         int tid)
{
  #pragma unroll
  for (int j = 0; j < R/128; j++){
    int row = j*128 + (tid >> 2);
    const unsigned short* src = gsrc + (size_t)row*ldE + (tid & 3)*8;
    __builtin_amdgcn_global_load_lds(
        (const __attribute__((address_space(1))) void*)src,
        (__attribute__((address_space(3))) void*)(lds + j*4096 + (tid >> 6)*512),
        16, 0, 0);
  }
}

__device__ __forceinline__ short8v rfrag(const unsigned short* lds, int r, int s){
  return *(const short8v*)((const char*)lds + r*64 + (s << 4));
}

#define WAITV(N)  asm volatile("s_waitcnt vmcnt(" #N ")" ::: "memory")
#define TOPBAR()  do { __builtin_amdgcn_s_barrier(); __builtin_amdgcn_sched_barrier(0); } while(0)
#define PIN()     do { asm volatile("s_waitcnt lgkmcnt(0)" ::: "memory"); __builtin_amdgcn_sched_barrier(0); } while(0)

// ------ GEMM1 + fused SwiGLU (r7's measured-best): 256 thr, 4 waves ------------
// BM=256, BN=128, wave 128x64 (2Mx2N), ring-3 (72KB -> 2 blocks/CU), dist-2,
// 6 vm-ops/tile, ladder WAITV(6)/6/0, grid 768 = 3 blocks/CU.
__global__ __launch_bounds__(256, 2) void gemm1_kernel(
    const unsigned short* __restrict__ xb, const unsigned short* __restrict__ gu,
    const float* __restrict__ wtg, unsigned short* __restrict__ actb)
{
  __shared__ unsigned short Al[3][8192];   // 3 x 16 KB (256x32)
  __shared__ unsigned short Bl[3][4096];   // 3 x  8 KB (128x32)
  int tid = threadIdx.x, lane = tid & 63, w = tid >> 6;
  int wm = w >> 1, wn = w & 1;
  int fr = lane & 15, sl = lane >> 4;

  int bid = blockIdx.x;
  int xcd = bid & 7, j = bid >> 3;
  int panel = ((xcd & 1) ? 48 : 0) + (j >> 1);
  int mb = ((xcd >> 1) << 1) + (j & 1);
  int nb = panel % 12, g = panel / 12;
  int m0 = mb * 256, n0 = nb * 128;
  const unsigned short* Abase = xb + (size_t)m0 * HDIM;
  const unsigned short* Bbase = gu + ((size_t)g * 1536 + n0) * HDIM;

  f32x4 acc[8][4];
  #pragma unroll
  for (int m=0;m<8;m++){
    #pragma unroll
    for (int n=0;n<4;n++) acc[m][n] = (f32x4){0,0,0,0};
  }

  #define BODY1(t, CB, SB, DOSTAGE) do { \
    const unsigned short* Ab = &Al[CB][0]; \
    const unsigned short* Bb = &Bl[CB][0]; \
    short8v av[8], bv[4]; \
    _Pragma("unroll") for (int m=0;m<8;m++) av[m] = rfrag(Ab, wm*128 + m*16 + fr, sl); \
    _Pragma("unroll") for (int n=0;n<4;n++) bv[n] = rfrag(Bb, wn*64 + n*16 + fr, sl); \
    if (DOSTAGE){ int k2 = (t)+2; \
      stage256<256>(Abase + k2*32, HDIM, &Al[SB][0], tid); \
      stage256<128>(Bbase + k2*32, HDIM, &Bl[SB][0], tid); } \
    PIN(); \
    __builtin_amdgcn_s_setprio(1); \
    _Pragma("unroll") for (int m=0;m<8;m++){ \
      _Pragma("unroll") for (int n=0;n<4;n++){ \
        acc[m][n] = __builtin_amdgcn_mfma_f32_16x16x32_bf16(av[m], bv[n], acc[m][n],0,0,0); } } \
    __builtin_amdgcn_s_setprio(0); \
  } while(0)

  const int NT = 64;   // 2048/32
  stage256<256>(Abase,      HDIM, &Al[0][0], tid);
  stage256<128>(Bbase,      HDIM, &Bl[0][0], tid);
  stage256<256>(Abase + 32, HDIM, &Al[1][0], tid);
  stage256<128>(Bbase + 32, HDIM, &Bl[1][0], tid);

  int cb = 0, sb = 2;
  for (int t = 0; t < NT-2; ++t){
    WAITV(6); TOPBAR();
    BODY1(t, cb, sb, 1);
    cb = (cb==2)?0:cb+1; sb = (sb==2)?0:sb+1;
  }
  WAITV(6); TOPBAR(); BODY1(NT-2, cb, sb, 0);
  cb = (cb==2)?0:cb+1;
  WAITV(0); TOPBAR(); BODY1(NT-1, cb, sb, 0);
  #undef BODY1

  // fused SwiGLU epilogue
  int r0 = (lane >> 4) * 4;
  int q0 = (n0 + wn*64) >> 5;
  #pragma unroll
  for (int m = 0; m < 8; m++){
    int trow = m0 + wm*128 + m*16 + r0;
    #pragma unroll
    for (int q = 0; q < 2; q++){
      int icol = (q0 + q)*16 + fr;
      #pragma unroll
      for (int jj = 0; jj < 4; jj++){
        int t = trow + jj;
        float wv = wtg[(size_t)t*NGRP + g];
        float gf = acc[m][2*q][jj];
        float uf = acc[m][2*q+1][jj];
        float sg = gf / (1.f + expf(-gf));
        actb[((size_t)g*T_TOK + t)*IDIM + icol] = f2b(sg * uf * wv);
      }
    }
  }
}

// ------ GEMM2 split-K=2 (4 groups each): r5's measured-best --------------------
// BM=128, BN=256, 512 thr, 8 waves (2Mx4N, wave 64x64), ring-4, dist-3,
// 3 vm-ops/tile, ladder WAITV(6)/6/3/0, grid 256 = 1 block/CU (8 waves/CU).
__global__ __launch_bounds__(512, 2) void gemm2_kernel(
    const unsigned short* __restrict__ actb, const unsigned short* __restrict__ dnb,
    float* __restrict__ part)
{
  __shared__ unsigned short Al[4][4096];   // 4 x  8 KB (128x32)
  __shared__ unsigned short Bl[4][8192];   // 4 x 16 KB (256x32)
  int tid = threadIdx.x, lane = tid & 63, w = tid >> 6;
  int wm = w >> 2, wn = w & 3;
  int fr = lane & 15, sl = lane >> 4;

  int bid = blockIdx.x;
  int xcd = bid & 7, j = bid >> 3;
  int panel = ((xcd & 1) ? 8 : 0) + (j >> 2);
  int mb = ((xcd >> 1) << 2) + (j & 3);
  int nb = panel & 7, z = panel >> 3;
  int m0 = mb * 128, n0 = nb * 256;

  f32x4 acc[4][4];
  #pragma unroll
  for (int m=0;m<4;m++){
    #pragma unroll
    for (int n=0;n<4;n++) acc[m][n] = (f32x4){0,0,0,0};
  }

  #define STAGE2(kt, b2) do { \
    int gi = (kt) / 24; int kk = ((kt) - gi*24) * 32; int gg = z*4 + gi; \
    stage512<128>(actb + ((size_t)gg*T_TOK + m0)*IDIM + kk, IDIM, &Al[b2][0], tid); \
    stage512<256>(dnb  + ((size_t)gg*HDIM + n0)*IDIM + kk, IDIM, &Bl[b2][0], tid); \
  } while(0)

  #define BODY2(t, DOSTAGE) do { \
    int buf = (t) & 3; \
    short8v av[4], bv[4]; \
    _Pragma("unroll") for (int m=0;m<4;m++) av[m] = rfrag(&Al[buf][0], wm*64 + m*16 + fr, sl); \
    _Pragma("unroll") for (int n=0;n<4;n++) bv[n] = rfrag(&Bl[buf][0], wn*64 + n*16 + fr, sl); \
    if (DOSTAGE){ int k2 = (t)+3; STAGE2(k2, k2 & 3); } \
    PIN(); \
    __builtin_amdgcn_s_setprio(1); \
    _Pragma("unroll") for (int m=0;m<4;m++){ \
      _Pragma("unroll") for (int n=0;n<4;n++){ \
        acc[m][n] = __builtin_amdgcn_mfma_f32_16x16x32_bf16(av[m], bv[n], acc[m][n],0,0,0); } } \
    __builtin_amdgcn_s_setprio(0); \
  } while(0)

  const int NT = 96;
  STAGE2(0, 0); STAGE2(1, 1); STAGE2(2, 2);

  for (int t = 0; t < NT-3; ++t){
    WAITV(6); TOPBAR();
    BODY2(t, 1);
  }
  WAITV(6); TOPBAR(); BODY2(NT-3, 0);
  WAITV(3); TOPBAR(); BODY2(NT-2, 0);
  WAITV(0); TOPBAR(); BODY2(NT-1, 0);
  #undef BODY2
  #undef STAGE2

  float* Cb = part + (size_t)z * T_TOK * HDIM;
  int r0 = (lane >> 4) * 4;
  #pragma unroll
  for (int m = 0; m < 4; m++){
    int row = m0 + wm*64 + m*16 + r0;
    #pragma unroll
    for (int n = 0; n < 4; n++){
      int cc = n0 + wn*64 + n*16 + fr;
      #pragma unroll
      for (int jj = 0; jj < 4; jj++){
        Cb[(size_t)(row + jj)*HDIM + cc] = acc[m][n][jj];
      }
    }
  }
}

// ---------------- Final reduce over 2 partials ---------------------------------
__global__ __launch_bounds__(256) void reduce_kernel(
    const float* __restrict__ p, float* __restrict__ o)
{
  size_t i = ((size_t)blockIdx.x*256 + threadIdx.x)*4;
  float4 a0 = *(const float4*)(p + i);
  float4 a1 = *(const float4*)(p + 4194304 + i);
  float4 r;
  r.x = a0.x + a1.x;
  r.y = a0.y + a1.y;
  r.z = a0.z + a1.z;
  r.w = a0.w + a1.w;
  *(float4*)(o + i) = r;
}

extern "C" void kernel_launch(void* const* d_in, const int* in_sizes, int n_in,
                              void* d_out, int out_size, void* d_ws, size_t ws_size,
                              hipStream_t stream)
{
  (void)in_sizes; (void)n_in; (void)out_size; (void)ws_size;
  const float* x   = (const float*)d_in[0];
  const float* gw  = (const float*)d_in[1];
  const float* gup = (const float*)d_in[2];
  const float* dnp = (const float*)d_in[3];
  const int*   mg  = (const int*)d_in[4];
  const int*   de  = (const int*)d_in[5];
  float* out = (float*)d_out;
  char* ws = (char*)d_ws;

  // layout: [wtg 64K][xb 8M][dnb 24M][actb 24M][gub 48M | part 32M aliased]
  float*          wtg  = (float*)(ws + 0);
  unsigned short* xb   = (unsigned short*)(ws + 65536);
  unsigned short* dnb  = (unsigned short*)(ws + 8454144);
  unsigned short* actb = (unsigned short*)(ws + 33619968);
  unsigned short* gub  = (unsigned short*)(ws + 58785792);   // dead before gemm2
  float*          part = (float*)(ws + 58785792);

  router_kernel<<<512, 256, 0, stream>>>(x, gw, mg, wtg, xb);
  convert_kernel<<<dim3(4608,1,8), 256, 0, stream>>>(gup, dnp, gub, dnb, de);
  gemm1_kernel<<<768, 256, 0, stream>>>(xb, gub, wtg, actb);
  gemm2_kernel<<<256, 512, 0, stream>>>(actb, dnb, part);
  reduce_kernel<<<4096, 256, 0, stream>>>(part, out);
}